// Round 9
// baseline (331.288 us; speedup 1.0000x reference)
//
#include <hip/hip_runtime.h>
#include <hip/hip_bf16.h>

// QLoRA forward: out = x @ dequant(q_w, scales)^T + 2.0 * (x @ A^T) @ B^T
// M=8192, N=4096, K=4096, rank=16, group=64.
// Round 9: m201 8-phase schedule, RACE-FIXED. r8 staged region hid=g of
// tile t+2 in the same phase as that region's last ds_reads (race -> absmax
// 7.4). Fix: stage hid=(g+3)&3, i.e. the region whose last read was the
// PREVIOUS phase (its readers all passed lgkmcnt(0)+barrier). vmcnt ledger
// re-derived: prologue 14 loads (t0 full + t1 hid0..2), vmcnt(6) at each
// tile's phase 0 = current tile complete, next tile's 6 loads in flight.

typedef unsigned short u16;
typedef __attribute__((ext_vector_type(8))) short bf16x8;
typedef __attribute__((ext_vector_type(4))) float f32x4;
typedef __attribute__((ext_vector_type(4))) int i32x4;

#define M_DIM 8192
#define N_DIM 4096
#define K_DIM 4096
#define BK 64
#define KT_MAIN 64
#define NT 65

// round-to-nearest-even f32 -> bf16
__device__ static inline u16 f2bf(float f) {
    union { float f; unsigned u; } v; v.f = f;
    unsigned r = v.u + 0x7fffu + ((v.u >> 16) & 1u);
    return (u16)(r >> 16);
}

__device__ static inline void gload16(const void* g, void* s) {
    __builtin_amdgcn_global_load_lds(
        (const __attribute__((address_space(1))) void*)g,
        (__attribute__((address_space(3))) void*)s, 16, 0, 0);
}

// ---------------- W dequant: Wb[o][k] = bf16(q[o][k] * scales[o][k/64]) -----
__global__ __launch_bounds__(256) void wprep_kernel(
        const int* __restrict__ q, const float* __restrict__ scales,
        u16* __restrict__ Wb) {
    int idx = blockIdx.x * 256 + threadIdx.x;
    int o  = idx >> 9;
    int kc = (idx & 511) << 3;
    float s = scales[(o << 6) + (kc >> 6)];
    const i32x4* qp = (const i32x4*)(q + (size_t)o * K_DIM + kc);
    i32x4 q0 = __builtin_nontemporal_load(qp);
    i32x4 q1 = __builtin_nontemporal_load(qp + 1);
    ushort4 r0, r1;
    r0.x = f2bf((float)q0.x * s); r0.y = f2bf((float)q0.y * s);
    r0.z = f2bf((float)q0.z * s); r0.w = f2bf((float)q0.w * s);
    r1.x = f2bf((float)q1.x * s); r1.y = f2bf((float)q1.y * s);
    r1.z = f2bf((float)q1.z * s); r1.w = f2bf((float)q1.w * s);
    *(ushort4*)&Wb[(size_t)o * K_DIM + kc]     = r0;
    *(ushort4*)&Wb[(size_t)o * K_DIM + kc + 4] = r1;
}

// ---------------- B2 pack: [4096][64] bf16, cols 16..63 = 0 ----------------
__global__ __launch_bounds__(256) void bprep_kernel(
        const float* __restrict__ lora_B, u16* __restrict__ B2) {
    int idx = blockIdx.x * 256 + threadIdx.x;   // 4096*64
    int o = idx >> 6, r = idx & 63;
    B2[idx] = (r < 16) ? f2bf(lora_B[o * 16 + r]) : (u16)0;
}

// ---------------- x prep (fused): xb = bf16(x); t2 = bf16(2 * x @ A^T) -----
__global__ __launch_bounds__(256) void xprep_kernel(
        const float* __restrict__ x, const float* __restrict__ lora_A,
        u16* __restrict__ xb, u16* __restrict__ t2) {
    const int tid = threadIdx.x, w = tid >> 6, l = tid & 63;
    const int rb = blockIdx.x * 8 + w * 2;
    float acc[2][16];
#pragma unroll
    for (int j = 0; j < 2; ++j)
#pragma unroll
        for (int r = 0; r < 16; ++r) acc[j][r] = 0.f;

    for (int i = 0; i < 16; ++i) {
        int k0 = i * 256 + l * 4;
        f32x4 x0 = __builtin_nontemporal_load(
                        (const f32x4*)&x[(size_t)rb * K_DIM + k0]);
        f32x4 x1 = __builtin_nontemporal_load(
                        (const f32x4*)&x[(size_t)(rb + 1) * K_DIM + k0]);
        ushort4 o0, o1;
        o0.x = f2bf(x0.x); o0.y = f2bf(x0.y); o0.z = f2bf(x0.z); o0.w = f2bf(x0.w);
        o1.x = f2bf(x1.x); o1.y = f2bf(x1.y); o1.z = f2bf(x1.z); o1.w = f2bf(x1.w);
        *(ushort4*)&xb[(size_t)rb * K_DIM + k0]       = o0;
        *(ushort4*)&xb[(size_t)(rb + 1) * K_DIM + k0] = o1;
#pragma unroll
        for (int r = 0; r < 16; ++r) {
            f32x4 av = *(const f32x4*)&lora_A[(size_t)r * K_DIM + k0];
            acc[0][r] += x0.x * av.x + x0.y * av.y + x0.z * av.z + x0.w * av.w;
            acc[1][r] += x1.x * av.x + x1.y * av.y + x1.z * av.z + x1.w * av.w;
        }
    }
#pragma unroll
    for (int j = 0; j < 2; ++j)
#pragma unroll
        for (int r = 0; r < 16; ++r) {
            float v = acc[j][r];
            v += __shfl_xor(v, 32); v += __shfl_xor(v, 16);
            v += __shfl_xor(v, 8);  v += __shfl_xor(v, 4);
            v += __shfl_xor(v, 2);  v += __shfl_xor(v, 1);
            acc[j][r] = v;
        }
    float lo = 0.f, hi = 0.f;
#pragma unroll
    for (int j = 0; j < 2; ++j)
#pragma unroll
        for (int c = 0; c < 8; ++c)
            if (l == j * 32 + c) { lo = acc[j][2 * c]; hi = acc[j][2 * c + 1]; }
    unsigned pack = (unsigned)f2bf(2.0f * lo) | ((unsigned)f2bf(2.0f * hi) << 16);
    *(unsigned*)&t2[(size_t)(rb + (l >> 5)) * 64 + (l & 31) * 2] = pack;
}

// ---------------- main GEMM (8-phase, race-fixed) --------------------------
// LDS buf (64KB): A [h][256 rows][32 k'] at h*16KB; B same at +32KB.
// Slot swizzle (16B slots, 4 per 64B row): phys = logical ^ ((row>>1)&3),
// realized by pre-swizzling the gload SOURCE (LDS dest stays linear).
// Regions: hid 0=B-kh0 (last read g0), 1=A-kh0 (g1), 2=B-kh1 (g2), 3=A-kh1 (g3).
// Phase g stages region (g+3)&3 -> one phase AFTER its last read.
__global__ __launch_bounds__(512, 2) void qlora_gemm(
        const u16* __restrict__ xb, const u16* __restrict__ Wb,
        const u16* __restrict__ t2, const u16* __restrict__ B2,
        float* __restrict__ out) {
    __shared__ u16 lds[2][32768];                 // 128 KB
    int bid = blockIdx.x;
    int swz = (bid & 7) * 64 + (bid >> 3);        // XCD bijective (512 = 8*64)
    int bn = swz >> 5;                            // 0..15
    int bm = swz & 31;                            // 0..31
    const int tid = threadIdx.x, w = tid >> 6, l = tid & 63;
    const int wr = w >> 2, wc = w & 3;            // 2x4 wave grid, 128x64/wave
    const int fr = l & 15, fq = l >> 4;
    const int slotSw = (fr >> 1) & 3;             // frag phys slot = fq ^ slotSw

    // staging: thread covers rows w*16 + (l>>2) (+128), phys slot l&3
    const int rowStage = w * 16 + (l >> 2);       // 0..127
    const int sw16 = (((l & 3) ^ ((l >> 3) & 3)) << 4);  // pre-swizzled src slot
    const int dstStage = w * 1024 + l * 16;       // linear LDS dest (8KB/gload)
    char* ldsC = (char*)&lds[0][0];

    // frag-read bases (within buffer): + i*1024 + h*16384 (A); + j*1024 (B)
    const int aoffH = (wr * 128 + fr) * 64 + ((fq ^ slotSw) << 4);
    const int boffH = 32768 + (wc * 64 + fr) * 64 + ((fq ^ slotSw) << 4);

    f32x4 acc[8][4] = {};
    bf16x8 ra[4], ra2[4], rbf[4];

    // stage one half-tile region: hid 0=B-kh0, 1=A-kh0, 2=B-kh1, 3=A-kh1
    auto stage_half = [&](int kt, int hid) {
        if (kt >= NT) return;
        int isB = ((hid & 1) == 0);
        int h = hid >> 1;
        char* dstR = ldsC + (kt & 1) * 65536 + (isB ? 32768 : 0) + h * 16384;
        int baseRow = (isB ? bn : bm) * 256 + rowStage;
        if (kt < KT_MAIN) {
            const char* src = isB ? (const char*)Wb : (const char*)xb;
            size_t so = (size_t)baseRow * 8192 + (size_t)kt * 128 + h * 64 + sw16;
            gload16(src + so, dstR + dstStage);
            gload16(src + so + (size_t)128 * 8192, dstR + dstStage + 8192);
        } else {                                  // lora: t2/B2 rows = 128B
            const char* src = isB ? (const char*)B2 : (const char*)t2;
            size_t so = (size_t)baseRow * 128 + h * 64 + sw16;
            gload16(src + so, dstR + dstStage);
            gload16(src + so + 128 * 128, dstR + dstStage + 8192);
        }
    };

    auto readG = [&](const char* cb, int g) {     // ds_reads for group g
        int h16 = (g >= 2) ? 16384 : 0;
        if ((g & 1) == 0) {                       // g0/g2: 4 B + 4 A (rows 0-63)
#pragma unroll
            for (int j = 0; j < 4; ++j)
                rbf[j] = *(const bf16x8*)(cb + boffH + h16 + j * 1024);
#pragma unroll
            for (int i = 0; i < 4; ++i)
                ra[i] = *(const bf16x8*)(cb + aoffH + h16 + i * 1024);
        } else {                                  // g1/g3: 4 A (rows 64-127)
#pragma unroll
            for (int i = 0; i < 4; ++i)
                ra2[i] = *(const bf16x8*)(cb + aoffH + h16 + (i + 4) * 1024);
        }
    };

    auto mfmaG = [&](int g) {                     // 16 MFMA for group g
        if ((g & 1) == 0) {
#pragma unroll
            for (int i = 0; i < 4; ++i)
#pragma unroll
                for (int j = 0; j < 4; ++j)
                    acc[i][j] = __builtin_amdgcn_mfma_f32_16x16x32_bf16(
                                    ra[i], rbf[j], acc[i][j], 0, 0, 0);
        } else {
#pragma unroll
            for (int i = 0; i < 4; ++i)
#pragma unroll
                for (int j = 0; j < 4; ++j)
                    acc[i + 4][j] = __builtin_amdgcn_mfma_f32_16x16x32_bf16(
                                        ra2[i], rbf[j], acc[i + 4][j], 0, 0, 0);
        }
    };

    // ---- prologue: tile 0 full + tile 1 hid0..2 = 14 loads ---------------
#pragma unroll
    for (int h = 0; h < 4; ++h) stage_half(0, h);
#pragma unroll
    for (int h = 0; h < 3; ++h) stage_half(1, h);
    asm volatile("s_waitcnt vmcnt(6)" ::: "memory");   // tile 0 landed
    __builtin_amdgcn_s_barrier();
    asm volatile("" ::: "memory");

    // ---- main loop: 32 iters x 2 K-tiles x 4 phases ----------------------
    for (int it = 0; it < 32; ++it) {
        const char* cb0 = ldsC;                    // tile 2it   -> buf0
        const char* cb1 = ldsC + 65536;            // tile 2it+1 -> buf1
#pragma unroll
        for (int p = 0; p < 8; ++p) {
            const char* cb = (p < 4) ? cb0 : cb1;
            int g = p & 3;
            int tcur = 2 * it + (p < 4 ? 0 : 1);
            // stage the region whose last read was the PREVIOUS phase
            int skt  = (g == 0) ? tcur + 1 : tcur + 2;
            int shid = (g + 3) & 3;
            if (g == 0)   // tile's first phase: counted vmcnt, never 0
                asm volatile("s_waitcnt vmcnt(6)" ::: "memory");
            readG(cb, g);
            stage_half(skt, shid);
            __builtin_amdgcn_sched_barrier(0);
            __builtin_amdgcn_s_barrier();
            asm volatile("s_waitcnt lgkmcnt(0)" ::: "memory");
            __builtin_amdgcn_sched_barrier(0);
            __builtin_amdgcn_s_setprio(1);
            mfmaG(g);
            __builtin_amdgcn_s_setprio(0);
            __builtin_amdgcn_sched_barrier(0);
            __builtin_amdgcn_s_barrier();
        }
    }

    // ---- tail: tile 64 (lora) in buf0, coarse ----------------------------
    asm volatile("s_waitcnt vmcnt(0)" ::: "memory");
    __builtin_amdgcn_s_barrier();
    asm volatile("" ::: "memory");
    {
        const char* cb = ldsC;                    // tile 64 -> buf 0
#pragma unroll
        for (int g = 0; g < 4; ++g) {
            readG(cb, g);
            asm volatile("s_waitcnt lgkmcnt(0)" ::: "memory");
            __builtin_amdgcn_sched_barrier(0);
            mfmaG(g);
        }
    }

    // epilogue: C/D layout col=lane&15, row=(lane>>4)*4+reg  [validated]
    float* obase = out + (size_t)(bm * 256 + wr * 128 + fq * 4) * N_DIM
                       + bn * 256 + wc * 64 + fr;
#pragma unroll
    for (int i = 0; i < 8; ++i)
#pragma unroll
        for (int j = 0; j < 4; ++j)
#pragma unroll
            for (int r = 0; r < 4; ++r)
                obase[(size_t)(i * 16 + r) * N_DIM + j * 16] = acc[i][j][r];
}

extern "C" void kernel_launch(void* const* d_in, const int* in_sizes, int n_in,
                              void* d_out, int out_size, void* d_ws, size_t ws_size,
                              hipStream_t stream) {
    const float* x      = (const float*)d_in[0];
    const int*   qw     = (const int*)d_in[1];
    const float* scales = (const float*)d_in[2];
    const float* lora_A = (const float*)d_in[3];
    const float* lora_B = (const float*)d_in[4];
    float* out = (float*)d_out;

    char* ws = (char*)d_ws;
    u16* xb = (u16*)(ws);                       // 8192*4096*2 = 67,108,864 B
    u16* Wb = (u16*)(ws + 67108864);            // 4096*4096*2 = 33,554,432 B
    u16* t2 = (u16*)(ws + 100663296);           // 8192*64*2   =  1,048,576 B
    u16* B2 = (u16*)(ws + 101711872);           // 4096*64*2   =    524,288 B

    wprep_kernel<<<8192, 256, 0, stream>>>(qw, scales, Wb);
    bprep_kernel<<<1024, 256, 0, stream>>>(lora_B, B2);
    xprep_kernel<<<1024, 256, 0, stream>>>(x, lora_A, xb, t2);
    qlora_gemm<<<dim3(512), 512, 0, stream>>>(xb, Wb, t2, B2, out);
}

// Round 10
// 314.146 us; speedup vs baseline: 1.0546x; 1.0546x over previous
//
#include <hip/hip_runtime.h>
#include <hip/hip_bf16.h>

// QLoRA forward: out = x @ dequant(q_w, scales)^T + 2.0 * (x @ A^T) @ B^T
// M=8192, N=4096, K=4096, rank=16, group=64.
// Round 10: r7 GEMM (best: BK=64, 2x64KB dbuf, 1 barrier/tile, reg-pipelined
// frag reads) + NEW XCD MAP: each XCD owns a 16bm x 4bn rectangle
// (was: 2bn x 32bm -> every A-panel hit all 8 XCDs; FETCH 556-670MB showed
// the GEMM is HBM-refetch-bound). Per-XCD set 68->40MB, A-panel sharing 8->4.

typedef unsigned short u16;
typedef __attribute__((ext_vector_type(8))) short bf16x8;
typedef __attribute__((ext_vector_type(4))) float f32x4;
typedef __attribute__((ext_vector_type(4))) int i32x4;

#define M_DIM 8192
#define N_DIM 4096
#define K_DIM 4096
#define BK 64
#define KT_MAIN 64
#define NT 65

// round-to-nearest-even f32 -> bf16
__device__ static inline u16 f2bf(float f) {
    union { float f; unsigned u; } v; v.f = f;
    unsigned r = v.u + 0x7fffu + ((v.u >> 16) & 1u);
    return (u16)(r >> 16);
}

__device__ static inline void gload16(const void* g, void* s) {
    __builtin_amdgcn_global_load_lds(
        (const __attribute__((address_space(1))) void*)g,
        (__attribute__((address_space(3))) void*)s, 16, 0, 0);
}

// ---------------- W dequant: Wb[o][k] = bf16(q[o][k] * scales[o][k/64]) -----
__global__ __launch_bounds__(256) void wprep_kernel(
        const int* __restrict__ q, const float* __restrict__ scales,
        u16* __restrict__ Wb) {
    int idx = blockIdx.x * 256 + threadIdx.x;
    int o  = idx >> 9;
    int kc = (idx & 511) << 3;
    float s = scales[(o << 6) + (kc >> 6)];
    const i32x4* qp = (const i32x4*)(q + (size_t)o * K_DIM + kc);
    i32x4 q0 = __builtin_nontemporal_load(qp);
    i32x4 q1 = __builtin_nontemporal_load(qp + 1);
    ushort4 r0, r1;
    r0.x = f2bf((float)q0.x * s); r0.y = f2bf((float)q0.y * s);
    r0.z = f2bf((float)q0.z * s); r0.w = f2bf((float)q0.w * s);
    r1.x = f2bf((float)q1.x * s); r1.y = f2bf((float)q1.y * s);
    r1.z = f2bf((float)q1.z * s); r1.w = f2bf((float)q1.w * s);
    *(ushort4*)&Wb[(size_t)o * K_DIM + kc]     = r0;
    *(ushort4*)&Wb[(size_t)o * K_DIM + kc + 4] = r1;
}

// ---------------- B2 pack: [4096][64] bf16, cols 16..63 = 0 ----------------
__global__ __launch_bounds__(256) void bprep_kernel(
        const float* __restrict__ lora_B, u16* __restrict__ B2) {
    int idx = blockIdx.x * 256 + threadIdx.x;   // 4096*64
    int o = idx >> 6, r = idx & 63;
    B2[idx] = (r < 16) ? f2bf(lora_B[o * 16 + r]) : (u16)0;
}

// ---------------- x prep (fused): xb = bf16(x); t2 = bf16(2 * x @ A^T) -----
// t2 is [8192][64], cols 16..63 zero.
__global__ __launch_bounds__(256) void xprep_kernel(
        const float* __restrict__ x, const float* __restrict__ lora_A,
        u16* __restrict__ xb, u16* __restrict__ t2) {
    const int tid = threadIdx.x, w = tid >> 6, l = tid & 63;
    const int rb = blockIdx.x * 8 + w * 2;     // wave's 2 rows
    float acc[2][16];
#pragma unroll
    for (int j = 0; j < 2; ++j)
#pragma unroll
        for (int r = 0; r < 16; ++r) acc[j][r] = 0.f;

    for (int i = 0; i < 16; ++i) {
        int k0 = i * 256 + l * 4;
        f32x4 x0 = __builtin_nontemporal_load(
                        (const f32x4*)&x[(size_t)rb * K_DIM + k0]);
        f32x4 x1 = __builtin_nontemporal_load(
                        (const f32x4*)&x[(size_t)(rb + 1) * K_DIM + k0]);
        ushort4 o0, o1;
        o0.x = f2bf(x0.x); o0.y = f2bf(x0.y); o0.z = f2bf(x0.z); o0.w = f2bf(x0.w);
        o1.x = f2bf(x1.x); o1.y = f2bf(x1.y); o1.z = f2bf(x1.z); o1.w = f2bf(x1.w);
        *(ushort4*)&xb[(size_t)rb * K_DIM + k0]       = o0;
        *(ushort4*)&xb[(size_t)(rb + 1) * K_DIM + k0] = o1;
#pragma unroll
        for (int r = 0; r < 16; ++r) {
            f32x4 av = *(const f32x4*)&lora_A[(size_t)r * K_DIM + k0];
            acc[0][r] += x0.x * av.x + x0.y * av.y + x0.z * av.z + x0.w * av.w;
            acc[1][r] += x1.x * av.x + x1.y * av.y + x1.z * av.z + x1.w * av.w;
        }
    }
#pragma unroll
    for (int j = 0; j < 2; ++j)
#pragma unroll
        for (int r = 0; r < 16; ++r) {
            float v = acc[j][r];
            v += __shfl_xor(v, 32); v += __shfl_xor(v, 16);
            v += __shfl_xor(v, 8);  v += __shfl_xor(v, 4);
            v += __shfl_xor(v, 2);  v += __shfl_xor(v, 1);
            acc[j][r] = v;
        }
    float lo = 0.f, hi = 0.f;
#pragma unroll
    for (int j = 0; j < 2; ++j)
#pragma unroll
        for (int c = 0; c < 8; ++c)
            if (l == j * 32 + c) { lo = acc[j][2 * c]; hi = acc[j][2 * c + 1]; }
    unsigned pack = (unsigned)f2bf(2.0f * lo) | ((unsigned)f2bf(2.0f * hi) << 16);
    *(unsigned*)&t2[(size_t)(rb + (l >> 5)) * 64 + (l & 31) * 2] = pack;
}

// ---------------- main GEMM ------------------------------------------------
// 256x256 tile, BK=64, 8 waves (2x4), LDS 2 bufs x (A 32KB + B 32KB) = 128KB.
// Row = 128B = 8 slots of 16B. Swizzle: phys slot p of row r holds logical
// slot p ^ (r&7); achieved by pre-swizzling the gload SOURCE (dest linear).
__global__ __launch_bounds__(512, 2) void qlora_gemm(
        const u16* __restrict__ xb, const u16* __restrict__ Wb,
        const u16* __restrict__ t2, const u16* __restrict__ B2,
        float* __restrict__ out) {
    __shared__ u16 lds[2][32768];                 // 128 KB
    // XCD map: XCD x owns 16bm x 4bn rectangle (bijective, 512 = 8*64).
    // A-panel shared by 4 XCDs (was 8), per-XCD input set 40MB (was 68MB).
    int bid = blockIdx.x;
    int x8 = bid & 7, sq = bid >> 3;              // x8 = XCD id (HW round-robin)
    int bm = (x8 & 1) * 16 + (sq & 15);           // 0..31
    int bn = (x8 >> 1) * 4 + (sq >> 4);           // 0..15
    const int tid = threadIdx.x, w = tid >> 6, l = tid & 63;
    const int wr = w >> 2, wc = w & 3;            // 2x4 wave grid, 128x64 per wave
    const int fr = l & 15, fq = l >> 4;
    const int s0 = fq ^ (fr & 7);                 // swizzled slot, kk=0
    // (kk=1 slot = s0 ^ 4)

    // ---- staging addresses: op o covers tile rows o*64 + w*8 + (l>>3) ----
    const int sw16 = ((l & 7) ^ ((l >> 3) & 7)) << 4;   // pre-swizzled src offset
    const int rl   = w * 8 + (l >> 3);                  // row within op-0 stripe
    const int rA0  = bm * 256 + rl;
    const int rB0  = bn * 256 + rl;
    char* ldsC = (char*)&lds[0][0];
    const int dst = w * 1024 + l * 16;            // + o*8192 (A), +32768 (B)

    // ---- fragment-read byte offsets (within a buffer) --------------------
    const int arow = (wr * 128 + fr) * 128;              // + i*2048 + slot*16
    const int brow = 32768 + (wc * 64 + fr) * 128;       // + j*2048 + slot*16

    f32x4 acc[8][4] = {};

    auto stage = [&](int kt, int buf) {           // 8 gloads: full 64KB tile
        char* base = ldsC + buf * 65536;
        if (kt < KT_MAIN) {
            size_t ko = (size_t)kt * 128;
#pragma unroll
            for (int o = 0; o < 4; ++o) {
                gload16((const char*)xb + ((size_t)(rA0 + o * 64) * 8192 + sw16) + ko,
                        base + dst + o * 8192);
                gload16((const char*)Wb + ((size_t)(rB0 + o * 64) * 8192 + sw16) + ko,
                        base + 32768 + dst + o * 8192);
            }
        } else {                                  // lora tile
#pragma unroll
            for (int o = 0; o < 4; ++o) {
                gload16((const char*)t2 + ((size_t)(rA0 + o * 64) * 128 + sw16),
                        base + dst + o * 8192);
                gload16((const char*)B2 + ((size_t)(rB0 + o * 64) * 128 + sw16),
                        base + 32768 + dst + o * 8192);
            }
        }
    };

    // ---------------- prologue ----------------
    stage(0, 0);
    asm volatile("s_waitcnt vmcnt(0)" ::: "memory");
    __builtin_amdgcn_s_barrier();
    asm volatile("" ::: "memory");

    bf16x8 a0[8], b0[4], a1[8], b1[4];
#pragma unroll
    for (int j = 0; j < 4; ++j)
        b0[j] = *(const bf16x8*)(ldsC + brow + j * 2048 + s0 * 16);
#pragma unroll
    for (int i = 0; i < 8; ++i)
        a0[i] = *(const bf16x8*)(ldsC + arow + i * 2048 + s0 * 16);

    for (int t = 0; t < NT; ++t) {
        const char* cb = ldsC + (t & 1) * 65536;

        // (1) kk1 frag reads — drain under kk0 MFMA
#pragma unroll
        for (int j = 0; j < 4; ++j)
            b1[j] = *(const bf16x8*)(cb + brow + j * 2048 + (s0 ^ 4) * 16);
#pragma unroll
        for (int i = 0; i < 8; ++i)
            a1[i] = *(const bf16x8*)(cb + arow + i * 2048 + (s0 ^ 4) * 16);
        // (2) next-tile staging — lands under this tile's compute
        if (t + 1 < NT) stage(t + 1, (t + 1) & 1);
        __builtin_amdgcn_sched_barrier(0);

        // (3) MFMA kk0 (a0/b0 long-landed)
        __builtin_amdgcn_s_setprio(1);
#pragma unroll
        for (int i = 0; i < 8; ++i)
#pragma unroll
            for (int j = 0; j < 4; ++j)
                acc[i][j] = __builtin_amdgcn_mfma_f32_16x16x32_bf16(
                                a0[i], b0[j], acc[i][j], 0, 0, 0);
        __builtin_amdgcn_s_setprio(0);
        __builtin_amdgcn_sched_barrier(0);

        // (4) protocol: buf-reads drained + next tile staged, then rendezvous
        asm volatile("s_waitcnt lgkmcnt(0)" ::: "memory");
        asm volatile("s_waitcnt vmcnt(0)" ::: "memory");
        __builtin_amdgcn_s_barrier();
        asm volatile("" ::: "memory");

        // (5) next-tile kk0 frag reads — drain under kk1 MFMA
        if (t + 1 < NT) {
            const char* nb = ldsC + ((t + 1) & 1) * 65536;
#pragma unroll
            for (int j = 0; j < 4; ++j)
                b0[j] = *(const bf16x8*)(nb + brow + j * 2048 + s0 * 16);
#pragma unroll
            for (int i = 0; i < 8; ++i)
                a0[i] = *(const bf16x8*)(nb + arow + i * 2048 + s0 * 16);
        }
        __builtin_amdgcn_sched_barrier(0);

        // (6) MFMA kk1
        __builtin_amdgcn_s_setprio(1);
#pragma unroll
        for (int i = 0; i < 8; ++i)
#pragma unroll
            for (int j = 0; j < 4; ++j)
                acc[i][j] = __builtin_amdgcn_mfma_f32_16x16x32_bf16(
                                a1[i], b1[j], acc[i][j], 0, 0, 0);
        __builtin_amdgcn_s_setprio(0);
        __builtin_amdgcn_sched_barrier(0);
    }

    // epilogue: C/D layout col=lane&15, row=(lane>>4)*4+reg  [validated]
    float* obase = out + (size_t)(bm * 256 + wr * 128 + fq * 4) * N_DIM
                       + bn * 256 + wc * 64 + fr;
#pragma unroll
    for (int i = 0; i < 8; ++i)
#pragma unroll
        for (int j = 0; j < 4; ++j)
#pragma unroll
            for (int r = 0; r < 4; ++r)
                obase[(size_t)(i * 16 + r) * N_DIM + j * 16] = acc[i][j][r];
}

extern "C" void kernel_launch(void* const* d_in, const int* in_sizes, int n_in,
                              void* d_out, int out_size, void* d_ws, size_t ws_size,
                              hipStream_t stream) {
    const float* x      = (const float*)d_in[0];
    const int*   qw     = (const int*)d_in[1];
    const float* scales = (const float*)d_in[2];
    const float* lora_A = (const float*)d_in[3];
    const float* lora_B = (const float*)d_in[4];
    float* out = (float*)d_out;

    char* ws = (char*)d_ws;
    u16* xb = (u16*)(ws);                       // 8192*4096*2 = 67,108,864 B
    u16* Wb = (u16*)(ws + 67108864);            // 4096*4096*2 = 33,554,432 B
    u16* t2 = (u16*)(ws + 100663296);           // 8192*64*2   =  1,048,576 B
    u16* B2 = (u16*)(ws + 101711872);           // 4096*64*2   =    524,288 B

    wprep_kernel<<<8192, 256, 0, stream>>>(qw, scales, Wb);
    bprep_kernel<<<1024, 256, 0, stream>>>(lora_B, B2);
    xprep_kernel<<<1024, 256, 0, stream>>>(x, lora_A, xb, t2);
    qlora_gemm<<<dim3(512), 512, 0, stream>>>(xb, Wb, t2, B2, out);
}